// Round 1
// baseline (223.078 us; speedup 1.0000x reference)
//
#include <hip/hip_runtime.h>
#include <math.h>

// Problem constants (fixed by setup_inputs): L=5, B=8, n=1024, d=64
#define LL 5
#define BB 8
#define NN 1024
#define DD 64
#define LB (LL * BB)          // 40 (l,b) pairs
#define SPLIT 8               // n-dimension split: blocks per (l,b)
#define ROWS (NN / SPLIT)     // 128 rows of Z per block
#define CH 32                 // rows staged per LDS chunk
#define ZC (2 * DD)           // Z = [X | Y] has 128 columns

// Workspace layout (in floats)
#define G_SZ (LB * ZC * ZC)   // 655360 floats: raw gram Z^T Z per (l,b)
#define S_SZ (LB * ZC)        // 5120 floats: column sums per (l,b)
#define R_OFF (G_SZ + S_SZ)   // ratio[40]

// Kernel 1: partial gram G += Zc^T Zc contribution (raw Z^T Z; centering later)
// grid = (SPLIT, LB), block = 256 threads (16x16), each thread owns 8x8 of G[128][128]
__global__ __launch_bounds__(256) void gram_kernel(const float* __restrict__ X,
                                                   const float* __restrict__ Y,
                                                   float* __restrict__ G,
                                                   float* __restrict__ S) {
    const int lb = blockIdx.y;
    const int nchunk = blockIdx.x;
    const int tid = threadIdx.x;
    const int tx = tid & 15;
    const int ty = tid >> 4;

    __shared__ float lds[CH][ZC];   // 32 x 128 floats = 16 KB

    float acc[8][8];
#pragma unroll
    for (int r = 0; r < 8; ++r)
#pragma unroll
        for (int c = 0; c < 8; ++c) acc[r][c] = 0.0f;

    float csum = 0.0f;

    const int row0 = nchunk * ROWS;
    const float4* X4 = (const float4*)(X + (size_t)lb * NN * DD);
    const float4* Y4 = (const float4*)(Y + (size_t)lb * NN * DD);
    // one row of X (or Y) = DD/4 = 16 float4s

    for (int outer = 0; outer < ROWS / CH; ++outer) {
        const int rbase = row0 + outer * CH;
        // Stage CH x ZC floats = CH*32 float4s; 256 threads -> 4 each, coalesced
#pragma unroll
        for (int k = 0; k < (CH * 32) / 256; ++k) {
            const int f = tid + k * 256;
            const int row = f >> 5;       // /32 float4 per Z-row
            const int q = f & 31;         // float4 within row
            float4 v;
            if (q < 16) v = X4[(rbase + row) * 16 + q];
            else        v = Y4[(rbase + row) * 16 + (q - 16)];
            *(float4*)&lds[row][q * 4] = v;
        }
        __syncthreads();

        // Column sums (threads 0..127 each own one Z column)
        if (tid < ZC) {
#pragma unroll
            for (int i = 0; i < CH; ++i) csum += lds[i][tid];
        }

        // Outer-product accumulation: G[ty*8+r][tx*8+c] += Z[i][ty*8+r]*Z[i][tx*8+c]
#pragma unroll 4
        for (int i = 0; i < CH; ++i) {
            float4 a0 = *(const float4*)&lds[i][ty * 8];
            float4 a1 = *(const float4*)&lds[i][ty * 8 + 4];
            float4 b0 = *(const float4*)&lds[i][tx * 8];
            float4 b1 = *(const float4*)&lds[i][tx * 8 + 4];
            float a[8] = {a0.x, a0.y, a0.z, a0.w, a1.x, a1.y, a1.z, a1.w};
            float b[8] = {b0.x, b0.y, b0.z, b0.w, b1.x, b1.y, b1.z, b1.w};
#pragma unroll
            for (int r = 0; r < 8; ++r)
#pragma unroll
                for (int c = 0; c < 8; ++c)
                    acc[r][c] = fmaf(a[r], b[c], acc[r][c]);
        }
        __syncthreads();
    }

    // Accumulate partials (SPLIT blocks per (l,b) contend) — device-scope fp32 atomics
    float* Glb = G + (size_t)lb * ZC * ZC;
#pragma unroll
    for (int r = 0; r < 8; ++r) {
        const int gi = ty * 8 + r;
#pragma unroll
        for (int c = 0; c < 8; ++c)
            atomicAdd(&Glb[gi * ZC + tx * 8 + c], acc[r][c]);
    }
    if (tid < ZC) atomicAdd(&S[lb * ZC + tid], csum);
}

// Kernel 2: apply centering Gc = G - s s^T / n on the fly; Frobenius sums -> ratio
// grid = LB blocks x 256 threads
__global__ __launch_bounds__(256) void reduce_kernel(const float* __restrict__ G,
                                                     const float* __restrict__ S,
                                                     float* __restrict__ R) {
    const int lb = blockIdx.x;
    const int tid = threadIdx.x;
    __shared__ float s_sh[ZC];
    __shared__ float red[3][4];
    if (tid < ZC) s_sh[tid] = S[lb * ZC + tid];
    __syncthreads();

    const float4* G4 = (const float4*)(G + (size_t)lb * ZC * ZC);
    float vxx = 0.0f, vyy = 0.0f, hxy = 0.0f;
    const float inv_n = 1.0f / (float)NN;
#pragma unroll
    for (int k = 0; k < (ZC * ZC / 4) / 256; ++k) {   // 16 float4s per thread
        const int e4 = tid + k * 256;
        const float4 g = G4[e4];
        const int i = e4 >> 5;             // row (128 floats = 32 float4 per row)
        const int j0 = (e4 & 31) << 2;     // starting column
        const float si = s_sh[i] * inv_n;
        const float c0 = g.x - si * s_sh[j0 + 0];
        const float c1 = g.y - si * s_sh[j0 + 1];
        const float c2 = g.z - si * s_sh[j0 + 2];
        const float c3 = g.w - si * s_sh[j0 + 3];
        const float sq = c0 * c0 + c1 * c1 + c2 * c2 + c3 * c3;
        if (i < DD) {
            if (j0 < DD) vxx += sq;   // Xc^T Xc block
            else         hxy += sq;   // Xc^T Yc block (hsic)
        } else {
            if (j0 >= DD) vyy += sq;  // Yc^T Yc block (skip transpose-dup block)
        }
    }
    // wave64 shuffle reduce, then cross-wave via LDS
#pragma unroll
    for (int off = 32; off; off >>= 1) {
        vxx += __shfl_down(vxx, off);
        vyy += __shfl_down(vyy, off);
        hxy += __shfl_down(hxy, off);
    }
    const int wave = tid >> 6;
    if ((tid & 63) == 0) { red[0][wave] = vxx; red[1][wave] = vyy; red[2][wave] = hxy; }
    __syncthreads();
    if (tid == 0) {
        float a = 0.0f, b = 0.0f, h = 0.0f;
        for (int w = 0; w < 4; ++w) { a += red[0][w]; b += red[1][w]; h += red[2][w]; }
        R[lb] = fabsf(h / (sqrtf(a) * sqrtf(b)));
    }
}

// Kernel 3: loss = mean_l( -log( mean_b(ratio) + eps ) )
__global__ void final_kernel(const float* __restrict__ R, float* __restrict__ out) {
    const int tid = threadIdx.x;   // 64 threads, one wave
    float v = (tid < LB) ? R[tid] : 0.0f;
    // sum within each aligned group of 8 lanes (one layer's B ratios)
    v += __shfl_xor(v, 1);
    v += __shfl_xor(v, 2);
    v += __shfl_xor(v, 4);
    float loss = 0.0f;
#pragma unroll
    for (int l = 0; l < LL; ++l) {
        const float sl = __shfl(v, l * BB);   // uniform: all lanes participate
        loss += -logf(sl * (1.0f / (float)BB) + 1e-8f);
    }
    if (tid == 0) out[0] = loss * (1.0f / (float)LL);
}

extern "C" void kernel_launch(void* const* d_in, const int* in_sizes, int n_in,
                              void* d_out, int out_size, void* d_ws, size_t ws_size,
                              hipStream_t stream) {
    const float* teacher = (const float*)d_in[0];
    const float* student = (const float*)d_in[1];
    float* ws = (float*)d_ws;
    float* G = ws;
    float* S = ws + G_SZ;
    float* R = ws + R_OFF;

    // G and S are atomically accumulated — zero them (capture-safe async memset)
    hipMemsetAsync(d_ws, 0, (size_t)(G_SZ + S_SZ) * sizeof(float), stream);

    dim3 grid1(SPLIT, LB);
    gram_kernel<<<grid1, 256, 0, stream>>>(teacher, student, G, S);
    reduce_kernel<<<LB, 256, 0, stream>>>(G, S, R);
    final_kernel<<<1, 64, 0, stream>>>(R, (float*)d_out);
}

// Round 2
// 100.472 us; speedup vs baseline: 2.2203x; 2.2203x over previous
//
#include <hip/hip_runtime.h>
#include <math.h>

// Problem constants (fixed by setup_inputs): L=5, B=8, n=1024, d=64
#define LL 5
#define BB 8
#define NN 1024
#define DD 64
#define LB (LL * BB)          // 40 (l,b) pairs
#define SPLIT 16              // n-dimension split: blocks per (l,b)
#define ROWS (NN / SPLIT)     // 64 rows of Z per block
#define ZC (2 * DD)           // Z = [X | Y] has 128 columns

// Workspace layout (floats)
#define G_SZ (LB * SPLIT * ZC * ZC)   // 10.5M floats (42 MB): per-block partial grams
#define S_SZ (LB * SPLIT * ZC)        // per-block partial column sums
#define ACC_OFF (G_SZ + S_SZ)         // 40 x 4 floats: {vxx, vyy, hxy, pad}

// Kernel 1: partial gram Gp[lb][nc] = Z_chunk^T Z_chunk (raw; centering later).
// grid = (SPLIT, LB), block = 256 (16x16), each thread owns 8x8 of the 128x128 gram.
// NO atomics — each block writes its own 64 KB slab with plain float4 stores.
__global__ __launch_bounds__(256) void gram_kernel(const float* __restrict__ X,
                                                   const float* __restrict__ Y,
                                                   float* __restrict__ Gp,
                                                   float* __restrict__ Sp) {
    const int lb = blockIdx.y;
    const int nc = blockIdx.x;
    const int tid = threadIdx.x;
    const int tx = tid & 15;
    const int ty = tid >> 4;

    __shared__ float lds[ROWS][ZC];   // 64 x 128 floats = 32 KB

    const int rbase = nc * ROWS;
    const float4* X4 = (const float4*)(X + (size_t)lb * NN * DD);
    const float4* Y4 = (const float4*)(Y + (size_t)lb * NN * DD);

    // Stage ROWS x ZC = 2048 float4s; 8 per thread, coalesced
#pragma unroll
    for (int k = 0; k < (ROWS * 32) / 256; ++k) {
        const int f = tid + k * 256;
        const int row = f >> 5;       // Z-row within chunk
        const int q = f & 31;         // float4 within row
        float4 v;
        if (q < 16) v = X4[(rbase + row) * 16 + q];
        else        v = Y4[(rbase + row) * 16 + (q - 16)];
        *(float4*)&lds[row][q * 4] = v;
    }
    __syncthreads();

    // Partial column sums (threads 0..127 own one Z column each; 2-way LDS alias = free)
    if (tid < ZC) {
        float csum = 0.0f;
#pragma unroll
        for (int i = 0; i < ROWS; ++i) csum += lds[i][tid];
        Sp[(lb * SPLIT + nc) * ZC + tid] = csum;
    }

    float acc[8][8];
#pragma unroll
    for (int r = 0; r < 8; ++r)
#pragma unroll
        for (int c = 0; c < 8; ++c) acc[r][c] = 0.0f;

#pragma unroll 4
    for (int i = 0; i < ROWS; ++i) {
        float4 a0 = *(const float4*)&lds[i][ty * 8];
        float4 a1 = *(const float4*)&lds[i][ty * 8 + 4];
        float4 b0 = *(const float4*)&lds[i][tx * 8];
        float4 b1 = *(const float4*)&lds[i][tx * 8 + 4];
        float a[8] = {a0.x, a0.y, a0.z, a0.w, a1.x, a1.y, a1.z, a1.w};
        float b[8] = {b0.x, b0.y, b0.z, b0.w, b1.x, b1.y, b1.z, b1.w};
#pragma unroll
        for (int r = 0; r < 8; ++r)
#pragma unroll
            for (int c = 0; c < 8; ++c)
                acc[r][c] = fmaf(a[r], b[c], acc[r][c]);
    }

    // Plain stores of this block's private partial gram (coalesced 512B per gi-row per wave)
    float* Gb = Gp + (size_t)(lb * SPLIT + nc) * (ZC * ZC);
#pragma unroll
    for (int r = 0; r < 8; ++r) {
        const int gi = ty * 8 + r;
        *(float4*)&Gb[gi * ZC + tx * 8]     = make_float4(acc[r][0], acc[r][1], acc[r][2], acc[r][3]);
        *(float4*)&Gb[gi * ZC + tx * 8 + 4] = make_float4(acc[r][4], acc[r][5], acc[r][6], acc[r][7]);
    }
}

// Kernel 2: sum the SPLIT partials, center on the fly (Gc = G - s s^T / n),
// accumulate Frobenius sums. grid = LB*4 blocks x 256 threads; each block owns
// a 32-row slab of one (l,b) gram; 3 atomicAdds per block into Acc.
__global__ __launch_bounds__(256) void reduce_kernel(const float* __restrict__ Gp,
                                                     const float* __restrict__ Sp,
                                                     float* __restrict__ Acc) {
    const int lb = blockIdx.x >> 2;
    const int q = blockIdx.x & 3;
    const int tid = threadIdx.x;
    __shared__ float s_sh[ZC];
    __shared__ float red[3][4];

    if (tid < ZC) {
        float s = 0.0f;
#pragma unroll
        for (int sp = 0; sp < SPLIT; ++sp) s += Sp[(lb * SPLIT + sp) * ZC + tid];
        s_sh[tid] = s;
    }
    __syncthreads();

    const float4* Gp4 = (const float4*)Gp;
    const size_t lb_base = (size_t)lb * SPLIT * (ZC * ZC / 4);
    float vxx = 0.0f, vyy = 0.0f, hxy = 0.0f;
    const float inv_n = 1.0f / (float)NN;
#pragma unroll
    for (int k = 0; k < 4; ++k) {
        const int e4 = q * 1024 + k * 256 + tid;   // float4 index within 128x128 gram
        float4 g = make_float4(0.f, 0.f, 0.f, 0.f);
#pragma unroll
        for (int sp = 0; sp < SPLIT; ++sp) {
            const float4 p = Gp4[lb_base + (size_t)sp * (ZC * ZC / 4) + e4];
            g.x += p.x; g.y += p.y; g.z += p.z; g.w += p.w;
        }
        const int i = e4 >> 5;             // gram row
        const int j0 = (e4 & 31) << 2;     // gram starting column
        const float si = s_sh[i] * inv_n;
        const float c0 = g.x - si * s_sh[j0 + 0];
        const float c1 = g.y - si * s_sh[j0 + 1];
        const float c2 = g.z - si * s_sh[j0 + 2];
        const float c3 = g.w - si * s_sh[j0 + 3];
        const float sq = c0 * c0 + c1 * c1 + c2 * c2 + c3 * c3;
        if (i < DD) {
            if (j0 < DD) vxx += sq;   // Xc^T Xc block
            else         hxy += sq;   // Xc^T Yc block
        } else {
            if (j0 >= DD) vyy += sq;  // Yc^T Yc block (YX block is a duplicate — skip)
        }
    }
#pragma unroll
    for (int off = 32; off; off >>= 1) {
        vxx += __shfl_down(vxx, off);
        vyy += __shfl_down(vyy, off);
        hxy += __shfl_down(hxy, off);
    }
    const int wave = tid >> 6;
    if ((tid & 63) == 0) { red[0][wave] = vxx; red[1][wave] = vyy; red[2][wave] = hxy; }
    __syncthreads();
    if (tid == 0) {
        float a = 0.0f, b = 0.0f, h = 0.0f;
#pragma unroll
        for (int w = 0; w < 4; ++w) { a += red[0][w]; b += red[1][w]; h += red[2][w]; }
        atomicAdd(&Acc[lb * 4 + 0], a);
        atomicAdd(&Acc[lb * 4 + 1], b);
        atomicAdd(&Acc[lb * 4 + 2], h);
    }
}

// Kernel 3: ratio[lb] = |h| / sqrt(a*b); loss = mean_l(-log(mean_b(ratio)+eps))
__global__ void final_kernel(const float* __restrict__ Acc, float* __restrict__ out) {
    const int tid = threadIdx.x;   // 64 threads, one wave
    float v = 0.0f;
    if (tid < LB) {
        const float a = Acc[tid * 4 + 0];
        const float b = Acc[tid * 4 + 1];
        const float h = Acc[tid * 4 + 2];
        v = fabsf(h / (sqrtf(a) * sqrtf(b)));
    }
    v += __shfl_xor(v, 1);
    v += __shfl_xor(v, 2);
    v += __shfl_xor(v, 4);
    float loss = 0.0f;
#pragma unroll
    for (int l = 0; l < LL; ++l) {
        const float sl = __shfl(v, l * BB);
        loss += -logf(sl * (1.0f / (float)BB) + 1e-8f);
    }
    if (tid == 0) out[0] = loss * (1.0f / (float)LL);
}

extern "C" void kernel_launch(void* const* d_in, const int* in_sizes, int n_in,
                              void* d_out, int out_size, void* d_ws, size_t ws_size,
                              hipStream_t stream) {
    const float* teacher = (const float*)d_in[0];
    const float* student = (const float*)d_in[1];
    float* ws = (float*)d_ws;
    float* Gp = ws;
    float* Sp = ws + G_SZ;
    float* Acc = ws + ACC_OFF;

    // Only the tiny scalar accumulators need zeroing now (atomically updated)
    hipMemsetAsync(Acc, 0, LB * 4 * sizeof(float), stream);

    dim3 grid1(SPLIT, LB);
    gram_kernel<<<grid1, 256, 0, stream>>>(teacher, student, Gp, Sp);
    reduce_kernel<<<LB * 4, 256, 0, stream>>>(Gp, Sp, Acc);
    final_kernel<<<1, 64, 0, stream>>>(Acc, (float*)d_out);
}

// Round 3
// 79.749 us; speedup vs baseline: 2.7973x; 1.2599x over previous
//
#include <hip/hip_runtime.h>
#include <math.h>

// Problem constants: L=5, B=8, n=1024, d=64
#define LL 5
#define BB 8
#define NN 1024
#define DD 64
#define LB (LL * BB)          // 40 (l,b) pairs
#define SPLIT 8               // n-split: blocks per (l,b)
#define ROWS (NN / SPLIT)     // 128 rows of Z per block
#define ZC (2 * DD)           // Z = [X | Y], 128 columns

// Workspace layout (floats)
#define G_SZ (LB * SPLIT * ZC * ZC)   // 5.24M floats (21 MB) partial grams
#define S_SZ (LB * SPLIT * ZC)        // partial column sums
#define ACC_OFF (G_SZ + S_SZ)         // 40 x 4 accumulators

typedef short short8 __attribute__((ext_vector_type(8)));   // 8 bf16 = 4 VGPRs
typedef float floatx4 __attribute__((ext_vector_type(4)));  // MFMA C/D

__device__ __forceinline__ unsigned short f2bf(float f) {
    union { float f; unsigned u; } v; v.f = f;
    const unsigned u = v.u;
    return (unsigned short)((u + 0x7FFFu + ((u >> 16) & 1u)) >> 16);  // RNE
}

// Zt LDS layout: col-major (K-contiguous) bf16 with XOR-octet swizzle.
// Element (c, k) lives at short-index: c*128 + ((k>>3) ^ (c&15))*8 + (k&7).
// Frag for tile base t, k-block k0: lane l -> Zt[t+(l&15)][k0 + (l>>4)*8 .. +8],
// one aligned 16B read, conflict-free (bank-quad = (o&7)^(c&7) uniform over wave).
__device__ __forceinline__ short8 read_frag(const short* Zt, int t, int lane, int k0) {
    const int c = t + (lane & 15);
    const int o = (k0 >> 3) + (lane >> 4);
    return *(const short8*)(Zt + c * 128 + ((o ^ (c & 15)) << 3));
}

// Kernel 1: partial gram Gp = (bf16 Z-chunk)^T (bf16 Z-chunk) via MFMA.
// grid (SPLIT, LB) x 256 threads (4 waves); wave w owns a 64x64 quadrant.
__global__ __launch_bounds__(256) void gram_kernel(const float* __restrict__ X,
                                                   const float* __restrict__ Y,
                                                   float* __restrict__ Gp,
                                                   float* __restrict__ Sp) {
    __shared__ short Zt[128 * 128];       // 32 KB swizzled bf16
    __shared__ float csum_sh[2][ZC];

    const int lb = blockIdx.y, nc = blockIdx.x, tid = threadIdx.x;
    const int c = tid & 127;              // Z column this thread stages
    const int half = tid >> 7;            // 0/1: which half of K
    const int rbase = nc * ROWS;

    const float* src = (c < DD) ? (X + (size_t)lb * NN * DD + c)
                                : (Y + (size_t)lb * NN * DD + (c - DD));

    // Stage: 32 k-pairs per thread; global reads coalesced (lane = consecutive col),
    // LDS writes packed 2 bf16 per b32 into the swizzled layout.
#pragma unroll 4
    for (int j = 0; j < 32; ++j) {
        const int kp = half * 32 + j;                    // k-pair index, k = 2kp
        const float v0 = src[(size_t)(rbase + 2 * kp) * DD];
        const float v1 = src[(size_t)(rbase + 2 * kp + 1) * DD];
        const unsigned val = (unsigned)f2bf(v0) | ((unsigned)f2bf(v1) << 16);
        const int o = kp >> 2, dw = kp & 3;              // octet, dword-in-octet
        *(unsigned*)((char*)Zt + (c << 8) + ((o ^ (c & 15)) << 4) + (dw << 2)) = val;
    }
    __syncthreads();

    // Column sums from the SAME bf16 data (centering stays self-consistent)
    {
        float s = 0.0f;
#pragma unroll
        for (int oo = 0; oo < 8; ++oo) {
            const int o = half * 8 + oo;
            const short8 v = *(const short8*)(Zt + c * 128 + ((o ^ (c & 15)) << 3));
#pragma unroll
            for (int e = 0; e < 8; ++e) {
                union { unsigned u; float f; } t2;
                t2.u = ((unsigned)(unsigned short)v[e]) << 16;
                s += t2.f;
            }
        }
        csum_sh[half][c] = s;
    }
    __syncthreads();
    if (tid < ZC) Sp[(lb * SPLIT + nc) * ZC + tid] = csum_sh[0][tid] + csum_sh[1][tid];

    // MFMA main: C = Zt^T Zt. A-frag and B-frag layouts are identical here.
    const int lane = tid & 63, w = tid >> 6;
    const int wr = (w >> 1) * 64, wc = (w & 1) * 64;

    floatx4 acc[4][4];
#pragma unroll
    for (int i = 0; i < 4; ++i)
#pragma unroll
        for (int j = 0; j < 4; ++j)
            acc[i][j] = (floatx4){0.f, 0.f, 0.f, 0.f};

#pragma unroll
    for (int k0 = 0; k0 < ROWS; k0 += 32) {
        short8 af[4], bf_[4];
#pragma unroll
        for (int i = 0; i < 4; ++i) af[i] = read_frag(Zt, wr + i * 16, lane, k0);
#pragma unroll
        for (int j = 0; j < 4; ++j) bf_[j] = read_frag(Zt, wc + j * 16, lane, k0);
#pragma unroll
        for (int i = 0; i < 4; ++i)
#pragma unroll
            for (int j = 0; j < 4; ++j)
                acc[i][j] = __builtin_amdgcn_mfma_f32_16x16x32_bf16(af[i], bf_[j], acc[i][j], 0, 0, 0);
    }

    // Store partial gram. C/D layout: col = lane&15, row = (lane>>4)*4 + reg.
    float* Gb = Gp + (size_t)(lb * SPLIT + nc) * (ZC * ZC);
    const int g = lane >> 4, cl = lane & 15;
#pragma unroll
    for (int i = 0; i < 4; ++i)
#pragma unroll
        for (int j = 0; j < 4; ++j)
#pragma unroll
            for (int r = 0; r < 4; ++r)
                Gb[(wr + i * 16 + g * 4 + r) * ZC + (wc + j * 16 + cl)] = acc[i][j][r];
}

// Kernel 2: sum SPLIT partials, center (Gc = G - s s^T / n), Frobenius-reduce.
// grid = LB*4 x 256; 3 atomicAdds per block.
__global__ __launch_bounds__(256) void reduce_kernel(const float* __restrict__ Gp,
                                                     const float* __restrict__ Sp,
                                                     float* __restrict__ Acc) {
    const int lb = blockIdx.x >> 2;
    const int q = blockIdx.x & 3;
    const int tid = threadIdx.x;
    __shared__ float s_sh[ZC];
    __shared__ float red[3][4];

    if (tid < ZC) {
        float s = 0.0f;
#pragma unroll
        for (int sp = 0; sp < SPLIT; ++sp) s += Sp[(lb * SPLIT + sp) * ZC + tid];
        s_sh[tid] = s;
    }
    __syncthreads();

    const float4* Gp4 = (const float4*)Gp;
    const size_t lb_base = (size_t)lb * SPLIT * (ZC * ZC / 4);
    float vxx = 0.0f, vyy = 0.0f, hxy = 0.0f;
    const float inv_n = 1.0f / (float)NN;
#pragma unroll
    for (int k = 0; k < 4; ++k) {
        const int e4 = q * 1024 + k * 256 + tid;
        float4 gsum = make_float4(0.f, 0.f, 0.f, 0.f);
#pragma unroll
        for (int sp = 0; sp < SPLIT; ++sp) {
            const float4 p = Gp4[lb_base + (size_t)sp * (ZC * ZC / 4) + e4];
            gsum.x += p.x; gsum.y += p.y; gsum.z += p.z; gsum.w += p.w;
        }
        const int i = e4 >> 5;
        const int j0 = (e4 & 31) << 2;
        const float si = s_sh[i] * inv_n;
        const float c0 = gsum.x - si * s_sh[j0 + 0];
        const float c1 = gsum.y - si * s_sh[j0 + 1];
        const float c2 = gsum.z - si * s_sh[j0 + 2];
        const float c3 = gsum.w - si * s_sh[j0 + 3];
        const float sq = c0 * c0 + c1 * c1 + c2 * c2 + c3 * c3;
        if (i < DD) {
            if (j0 < DD) vxx += sq;
            else         hxy += sq;
        } else {
            if (j0 >= DD) vyy += sq;
        }
    }
#pragma unroll
    for (int off = 32; off; off >>= 1) {
        vxx += __shfl_down(vxx, off);
        vyy += __shfl_down(vyy, off);
        hxy += __shfl_down(hxy, off);
    }
    const int wave = tid >> 6;
    if ((tid & 63) == 0) { red[0][wave] = vxx; red[1][wave] = vyy; red[2][wave] = hxy; }
    __syncthreads();
    if (tid == 0) {
        float a = 0.0f, b = 0.0f, h = 0.0f;
#pragma unroll
        for (int wv = 0; wv < 4; ++wv) { a += red[0][wv]; b += red[1][wv]; h += red[2][wv]; }
        atomicAdd(&Acc[lb * 4 + 0], a);
        atomicAdd(&Acc[lb * 4 + 1], b);
        atomicAdd(&Acc[lb * 4 + 2], h);
    }
}

// Kernel 3: ratio -> loss
__global__ void final_kernel(const float* __restrict__ Acc, float* __restrict__ out) {
    const int tid = threadIdx.x;   // one wave
    float v = 0.0f;
    if (tid < LB) {
        const float a = Acc[tid * 4 + 0];
        const float b = Acc[tid * 4 + 1];
        const float h = Acc[tid * 4 + 2];
        v = fabsf(h / (sqrtf(a) * sqrtf(b)));
    }
    v += __shfl_xor(v, 1);
    v += __shfl_xor(v, 2);
    v += __shfl_xor(v, 4);
    float loss = 0.0f;
#pragma unroll
    for (int l = 0; l < LL; ++l) {
        const float sl = __shfl(v, l * BB);
        loss += -logf(sl * (1.0f / (float)BB) + 1e-8f);
    }
    if (tid == 0) out[0] = loss * (1.0f / (float)LL);
}

extern "C" void kernel_launch(void* const* d_in, const int* in_sizes, int n_in,
                              void* d_out, int out_size, void* d_ws, size_t ws_size,
                              hipStream_t stream) {
    const float* teacher = (const float*)d_in[0];
    const float* student = (const float*)d_in[1];
    float* ws = (float*)d_ws;
    float* Gp = ws;
    float* Sp = ws + G_SZ;
    float* Acc = ws + ACC_OFF;

    hipMemsetAsync(Acc, 0, LB * 4 * sizeof(float), stream);

    dim3 grid1(SPLIT, LB);
    gram_kernel<<<grid1, 256, 0, stream>>>(teacher, student, Gp, Sp);
    reduce_kernel<<<LB * 4, 256, 0, stream>>>(Gp, Sp, Acc);
    final_kernel<<<1, 64, 0, stream>>>(Acc, (float*)d_out);
}